// Round 10
// baseline (294.692 us; speedup 1.0000x reference)
//
#include <hip/hip_runtime.h>

// PEG_Shift: depthwise 3x3 conv (stride 1, pad 1, groups=C), power-of-two weights,
// 16-bit fixed-point activations/bias. x: (32,384,56,56) f32.
//
// v9: barrier-free full-row register streaming.
//   Evidence (r1-r8): every stage->barrier->compute variant lands ~96us with ALL
//   pipes <=40% and pipe-times SUMMING to dur -> phase-locked cohorts serialize
//   HBM vs VALU vs LDS. v3/v6's zero-LDS attempt failed on 224B-strided wave
//   loads (64 lines/load). v9 fixes both:
//   - 16-lane group owns a FULL 56-wide row band (14 lanes x 4 cols), walks 14
//     rows with a 3-row quantized register window -> wave load = 4 rows x 224B
//     contiguous = 16 lines (perfect coalescing), qfix once per element
//   - horizontal halo via __shfl of quantized values (DS pipe, no LDS, no loads)
//   - 1 wave = 1 plane, 4 planes/block, 3072 blocks, no barriers anywhere
//   - 2-deep row prefetch; weights/bias pre-quantized into d_ws

#define DW_C   384
#define DW_H   56
#define DW_W   56
#define DW_HW  3136

__device__ __forceinline__ float qfix(float v) {
    // floor(v * 2^16) * 2^-16, clip [-2^15, 2^15-1] — exact in fp32
    v = floorf(v * 65536.0f) * (1.0f / 65536.0f);
    return fminf(fmaxf(v, -32768.0f), 32767.0f);   // v_med3_f32
}

struct RowQ { float l, a, b, c, d, r; };

// ---- pre-kernel: quantize 3456 weights (power of two) + 384 biases into d_ws ----
__global__ __launch_bounds__(256) void quant_wb(
    const float* __restrict__ wgt, const float* __restrict__ bias,
    float* __restrict__ wq, float* __restrict__ bq)
{
    int i = blockIdx.x * 256 + threadIdx.x;
    if (i < DW_C * 9) {
        float wv = wgt[i];
        float aw = fabsf(wv);
        float cw = fminf(fmaxf(aw, 6.103515625e-05f /*2^-14*/), 1.0f);
        float q  = exp2f(rintf(log2f(cw)));        // rint = round-half-even (jnp.round)
        wq[i] = (wv > 0.0f) ? q : ((wv < 0.0f) ? -q : 0.0f);
    }
    if (i < DW_C) bq[i] = qfix(bias[i]);
}

template<bool PRE>
__global__ __launch_bounds__(256, 8) void peg_shift_v9(
    const float* __restrict__ x, const float* __restrict__ wgt,
    const float* __restrict__ bias, float* __restrict__ out,
    const float* __restrict__ wsq, const float* __restrict__ wsb)
{
    const int tid   = threadIdx.x;
    const int wave  = tid >> 6;                  // 0..3: one plane per wave
    const int lane  = tid & 63;
    const int g     = lane >> 4;                 // 0..3: 14-row band within plane
    const int j     = lane & 15;                 // 0..15; j<14 active (56 = 14*4)
    const int plane = blockIdx.x * 4 + wave;
    const int c     = plane % DW_C;
    const int rb    = g * 14;                    // band rows rb..rb+13
    const int rlim  = min(rb + 15, DW_H);        // loads allowed rb-1..rb+14

    const bool act  = (j < 14);
    const int  jc   = act ? j : 13;              // clamp idle lanes' addresses

    // ---- per-channel quantized weights + bias (wave-uniform -> scalar loads) ----
    float ww[9], bqv;
    if (PRE) {
        const float* wp = wsq + c * 9;
#pragma unroll
        for (int t = 0; t < 9; ++t) ww[t] = wp[t];
        bqv = wsb[c];
    } else {
        const float* wp = wgt + c * 9;
#pragma unroll
        for (int t = 0; t < 9; ++t) {
            float wv = wp[t];
            float aw = fabsf(wv);
            float cw = fminf(fmaxf(aw, 6.103515625e-05f), 1.0f);
            float q  = exp2f(rintf(log2f(cw)));
            ww[t] = (wv > 0.0f) ? q : ((wv < 0.0f) ? -q : 0.0f);
        }
        bqv = qfix(bias[c]);
    }

    const float* xb = x + (size_t)plane * DW_HW + jc * 4;

    // raw row load: lanes of the wave cover 4 rows x 224B contiguous = 16 lines
    auto loadraw = [&](int rr) -> float4 {
        float4 m; m.x = m.y = m.z = m.w = 0.0f;
        if (rr >= 0 && rr < rlim) m = *(const float4*)(xb + rr * DW_W);
        return m;
    };

    // quantize once + horizontal halo from neighbors' quantized values via shfl
    auto mkrow = [&](float4 m) -> RowQ {
        RowQ q;
        q.a = qfix(m.x); q.b = qfix(m.y); q.c = qfix(m.z); q.d = qfix(m.w);
        float lu = __shfl_up(q.d, 1);            // lane j-1's col 4j-1
        float rd = __shfl_down(q.a, 1);          // lane j+1's col 4j+4
        q.l = (j == 0)  ? 0.0f : lu;             // left edge + group boundary
        q.r = (j >= 13) ? 0.0f : rd;             // right edge + idle-lane garbage
        return q;
    };

    // ---- prologue: window rows rb-1..rb+1 quantized; rb+2 raw in flight ----
    float4 mP = loadraw(rb + 2);
    RowQ A = mkrow(loadraw(rb - 1));
    RowQ B = mkrow(loadraw(rb));
    RowQ C = mkrow(loadraw(rb + 1));

    float* ob = out + (size_t)plane * DW_HW + rb * DW_W + j * 4;

#define ROWF(RW, W0, W1, W2)                                          \
    o0 = fmaf(RW.l, W0, fmaf(RW.a, W1, fmaf(RW.b, W2, o0)));          \
    o1 = fmaf(RW.a, W0, fmaf(RW.b, W1, fmaf(RW.c, W2, o1)));          \
    o2 = fmaf(RW.b, W0, fmaf(RW.c, W1, fmaf(RW.d, W2, o2)));          \
    o3 = fmaf(RW.c, W0, fmaf(RW.d, W1, fmaf(RW.r, W2, o3)));

#pragma unroll
    for (int i = 0; i < 14; ++i) {
        // 2-deep prefetch: row rb+i+3 issued while rb+i+2 (mP) is in flight
        float4 mQ = loadraw(rb + i + 3);

        float o0 = bqv, o1 = bqv, o2 = bqv, o3 = bqv;
        ROWF(A, ww[0], ww[1], ww[2])
        ROWF(B, ww[3], ww[4], ww[5])
        ROWF(C, ww[6], ww[7], ww[8])

        if (act) {
            float4 ov; ov.x = o0; ov.y = o1; ov.z = o2; ov.w = o3;
            *(float4*)ob = ov;
        }
        ob += DW_W;

        // rotate window (register renaming under full unroll)
        A = B; B = C;
        C = mkrow(mP);
        mP = mQ;
    }
#undef ROWF
}

extern "C" void kernel_launch(void* const* d_in, const int* in_sizes, int n_in,
                              void* d_out, int out_size, void* d_ws, size_t ws_size,
                              hipStream_t stream) {
    const float* x = (const float*)d_in[0];
    const float* w = (const float*)d_in[1];
    const float* b = (const float*)d_in[2];
    float* out = (float*)d_out;

    int planes  = in_sizes[0] / DW_HW;   // 32*384 = 12288
    int nblocks = planes / 4;            // 3072 blocks, 1 plane per wave

    size_t need = (size_t)(DW_C * 9 + DW_C) * sizeof(float);
    if (d_ws && ws_size >= need) {
        float* wq = (float*)d_ws;
        float* bq = wq + DW_C * 9;
        quant_wb<<<(DW_C * 9 + 255) / 256, 256, 0, stream>>>(w, b, wq, bq);
        peg_shift_v9<true><<<nblocks, 256, 0, stream>>>(x, w, b, out, wq, bq);
    } else {
        peg_shift_v9<false><<<nblocks, 256, 0, stream>>>(x, w, b, out, nullptr, nullptr);
    }
}